// Round 1
// baseline (2288.951 us; speedup 1.0000x reference)
//
#include <hip/hip_runtime.h>
#include <cstdint>
#include <cstddef>

// ---------------------------------------------------------------- types
typedef __bf16 bf16x8 __attribute__((ext_vector_type(8)));
typedef float  f32x4  __attribute__((ext_vector_type(4)));

#define BATCH 2
#define SEQ   2048
#define DMODEL 2048
#define NHQ   16
#define NHKV  8
#define HDIM  128
#define FFDIM 8192
#define NTOK  4096          // BATCH*SEQ

__device__ inline f32x4 mfma16(bf16x8 a, bf16x8 b, f32x4 c) {
    return __builtin_amdgcn_mfma_f32_16x16x32_bf16(a, b, c, 0, 0, 0);
}

__device__ inline float wave_sum64(float v) {
    v += __shfl_xor(v, 1);  v += __shfl_xor(v, 2);  v += __shfl_xor(v, 4);
    v += __shfl_xor(v, 8);  v += __shfl_xor(v, 16); v += __shfl_xor(v, 32);
    return v;
}

__device__ inline float block_sum256(float v, float* lds4) {
    v = wave_sum64(v);
    const int w = threadIdx.x >> 6;
    __syncthreads();                       // protect lds4 from previous use
    if ((threadIdx.x & 63) == 0) lds4[w] = v;
    __syncthreads();
    return lds4[0] + lds4[1] + lds4[2] + lds4[3];
}

// ---------------------------------------------------------------- weight convert: f32 [K][N] -> bf16 [N][K]
__global__ void transpose_cvt(const float* __restrict__ src, __bf16* __restrict__ dst,
                              int K, int N) {
    __shared__ float tile[32][33];
    const int tx = threadIdx.x, ty = threadIdx.y;
    const int n0 = blockIdx.x * 32, k0 = blockIdx.y * 32;
    #pragma unroll
    for (int i = 0; i < 4; ++i)
        tile[ty + i * 8][tx] = src[(size_t)(k0 + ty + i * 8) * N + n0 + tx];
    __syncthreads();
    #pragma unroll
    for (int i = 0; i < 4; ++i)
        dst[(size_t)(n0 + ty + i * 8) * K + k0 + tx] = (__bf16)tile[tx][ty + i * 8];
}

// bf16 [R][C] -> [C][R], per head (grid.z)
__global__ void transpose_bf16_k(const __bf16* __restrict__ src0, __bf16* __restrict__ dst0,
                                 int R, int C) {
    __shared__ __bf16 tile[32][34];
    const int z = blockIdx.z;
    const __bf16* src = src0 + (size_t)z * R * C;
    __bf16* dst = dst0 + (size_t)z * R * C;
    const int tx = threadIdx.x, ty = threadIdx.y;
    const int c0 = blockIdx.x * 32, r0 = blockIdx.y * 32;
    #pragma unroll
    for (int i = 0; i < 4; ++i)
        tile[ty + i * 8][tx] = src[(size_t)(r0 + ty + i * 8) * C + c0 + tx];
    __syncthreads();
    #pragma unroll
    for (int i = 0; i < 4; ++i)
        dst[(size_t)(c0 + ty + i * 8) * R + r0 + tx] = tile[tx][ty + i * 8];
}

// ---------------------------------------------------------------- embedding gather
__global__ __launch_bounds__(256) void embed_k(const float* __restrict__ emb,
                                               const int* __restrict__ ids,
                                               float* __restrict__ x) {
    const int row = blockIdx.x, t = threadIdx.x;
    const int id = ids[row];
    const size_t src = (size_t)id * DMODEL, dst = (size_t)row * DMODEL;
    const float sc = 45.2548339959390f;   // sqrt(2048)
    float4 a = *(const float4*)&emb[src + t * 4];
    float4 b = *(const float4*)&emb[src + t * 4 + 1024];
    a.x *= sc; a.y *= sc; a.z *= sc; a.w *= sc;
    b.x *= sc; b.y *= sc; b.z *= sc; b.w *= sc;
    *(float4*)&x[dst + t * 4] = a;
    *(float4*)&x[dst + t * 4 + 1024] = b;
}

// ---------------------------------------------------------------- segment-id scan (cumsum of position resets)
__global__ __launch_bounds__(256) void seg_scan(const int* __restrict__ pos,
                                                int* __restrict__ seg) {
    __shared__ int wsum[4];
    const int b = blockIdx.x, t = threadIdx.x;
    const int lane = t & 63, wv = t >> 6;
    const int base = b * SEQ;
    int f[8]; int loc = 0;
    #pragma unroll
    for (int i = 0; i < 8; ++i) {
        int s = t * 8 + i;
        int fl = (s > 0) ? (pos[base + s] <= pos[base + s - 1]) : 0;
        f[i] = fl; loc += fl;
    }
    int sc = loc;
    for (int o = 1; o < 64; o <<= 1) { int n = __shfl_up(sc, o); if (lane >= o) sc += n; }
    if (lane == 63) wsum[wv] = sc;
    __syncthreads();
    int wb = 0;
    for (int i = 0; i < wv; ++i) wb += wsum[i];
    int run = wb + sc - loc + 1;
    #pragma unroll
    for (int i = 0; i < 8; ++i) { run += f[i]; seg[base + t * 8 + i] = run; }
}

// ---------------------------------------------------------------- fused residual add + rmsnorm
// MODE 0: out_bf = rms(x, wB)                      (x unchanged)
// MODE 1: x += rms(h, wA); out_bf = rms(x, wB)
// MODE 2: x += rms(h, wA); out_f  = rms(x, wB)     (final output)
template<int MODE>
__global__ __launch_bounds__(256) void fused_norm_k(
        float* __restrict__ x, const float* __restrict__ h,
        const float* __restrict__ wA, const float* __restrict__ wB,
        __bf16* __restrict__ outb, float* __restrict__ outf) {
    __shared__ float lds4[4];
    const int row = blockIdx.x, t = threadIdx.x;
    const size_t base = (size_t)row * DMODEL;
    const int c0 = t * 4, c1 = t * 4 + 1024;
    float v[8];
    if constexpr (MODE == 0) {
        float4 a = *(const float4*)&x[base + c0];
        float4 b = *(const float4*)&x[base + c1];
        v[0]=a.x; v[1]=a.y; v[2]=a.z; v[3]=a.w;
        v[4]=b.x; v[5]=b.y; v[6]=b.z; v[7]=b.w;
    } else {
        float4 ha = *(const float4*)&h[base + c0];
        float4 hb = *(const float4*)&h[base + c1];
        float hv[8] = {ha.x, ha.y, ha.z, ha.w, hb.x, hb.y, hb.z, hb.w};
        float ss = 0.f;
        #pragma unroll
        for (int i = 0; i < 8; ++i) ss += hv[i] * hv[i];
        float tot = block_sum256(ss, lds4);
        float rs = rsqrtf(tot * (1.f / DMODEL) + 1e-6f);
        float4 xa = *(const float4*)&x[base + c0];
        float4 xb = *(const float4*)&x[base + c1];
        float xv[8] = {xa.x, xa.y, xa.z, xa.w, xb.x, xb.y, xb.z, xb.w};
        #pragma unroll
        for (int i = 0; i < 8; ++i) {
            int c = (i < 4) ? c0 + i : c1 + i - 4;
            v[i] = xv[i] + hv[i] * rs * (1.f + wA[c]);
        }
        float4 o0 = {v[0], v[1], v[2], v[3]}, o1 = {v[4], v[5], v[6], v[7]};
        *(float4*)&x[base + c0] = o0;
        *(float4*)&x[base + c1] = o1;
    }
    float ss2 = 0.f;
    #pragma unroll
    for (int i = 0; i < 8; ++i) ss2 += v[i] * v[i];
    float tot2 = block_sum256(ss2, lds4);
    float rs2 = rsqrtf(tot2 * (1.f / DMODEL) + 1e-6f);
    #pragma unroll
    for (int i = 0; i < 8; ++i) {
        int c = (i < 4) ? c0 + i : c1 + i - 4;
        float o = v[i] * rs2 * (1.f + wB[c]);
        if constexpr (MODE == 2) outf[base + c] = o;
        else outb[base + c] = (__bf16)o;
    }
}

// ---------------------------------------------------------------- NT GEMM: C[M][N] = A[M][K] * Bw[N][K]^T (bf16 in, f32 acc)
template<typename OutT>
__global__ __launch_bounds__(256) void gemm_nt(const __bf16* __restrict__ A,
                                               const __bf16* __restrict__ Bw,
                                               OutT* __restrict__ C,
                                               int M, int N, int K) {
    __shared__ __align__(16) __bf16 As[128][72];   // BK=64 + pad 8
    __shared__ __align__(16) __bf16 Bs[128][72];
    const int bm = blockIdx.y * 128, bn = blockIdx.x * 128;
    const int t = threadIdx.x;
    const int w = t >> 6, lane = t & 63;
    const int wm = (w >> 1) * 64, wn = (w & 1) * 64;
    const int lg = lane >> 4, lr = lane & 15;
    f32x4 acc[4][4] = {};
    for (int k0 = 0; k0 < K; k0 += 64) {
        #pragma unroll
        for (int i = 0; i < 4; ++i) {
            int c = t + i * 256;
            int row = c >> 3, col = (c & 7) * 8;
            *(int4*)&As[row][col] = *(const int4*)&A[(size_t)(bm + row) * K + k0 + col];
            *(int4*)&Bs[row][col] = *(const int4*)&Bw[(size_t)(bn + row) * K + k0 + col];
        }
        __syncthreads();
        #pragma unroll
        for (int kk = 0; kk < 2; ++kk) {
            bf16x8 af[4], bfr[4];
            #pragma unroll
            for (int m = 0; m < 4; ++m) af[m]  = *(const bf16x8*)&As[wm + m * 16 + lr][kk * 32 + lg * 8];
            #pragma unroll
            for (int n = 0; n < 4; ++n) bfr[n] = *(const bf16x8*)&Bs[wn + n * 16 + lr][kk * 32 + lg * 8];
            #pragma unroll
            for (int m = 0; m < 4; ++m)
                #pragma unroll
                for (int n = 0; n < 4; ++n)
                    acc[m][n] = mfma16(af[m], bfr[n], acc[m][n]);
        }
        __syncthreads();
    }
    #pragma unroll
    for (int m = 0; m < 4; ++m)
        #pragma unroll
        for (int n = 0; n < 4; ++n)
            #pragma unroll
            for (int r = 0; r < 4; ++r) {
                int row = bm + wm + m * 16 + lg * 4 + r;
                int col = bn + wn + n * 16 + lr;
                C[(size_t)row * N + col] = (OutT)acc[m][n][r];
            }
}

// ---------------------------------------------------------------- QKV post: per-head rmsnorm (q,k) + RoPE + bf16 head-major layouts
__global__ __launch_bounds__(256) void qkv_post(const float* __restrict__ qkv,
                                                const float* __restrict__ qnw,
                                                const float* __restrict__ knw,
                                                const int* __restrict__ posid,
                                                __bf16* __restrict__ qg,
                                                __bf16* __restrict__ kg,
                                                __bf16* __restrict__ vg) {
    const int slot = blockIdx.x * 4 + (threadIdx.x >> 6);
    const int lane = threadIdx.x & 63;
    const int token = slot >> 5, j = slot & 31;
    const int b = token >> 11, s = token & (SEQ - 1);
    int base;
    const float* nw = nullptr;
    if (j < 16)      { base = j * 128;                nw = qnw; }
    else if (j < 24) { base = 2048 + (j - 16) * 128;  nw = knw; }
    else             { base = 3072 + (j - 24) * 128; }
    float e0 = qkv[(size_t)token * 4096 + base + lane];
    float e1 = qkv[(size_t)token * 4096 + base + lane + 64];
    if (j < 24) {
        float ss = wave_sum64(e0 * e0 + e1 * e1);
        float rs = rsqrtf(ss * (1.f / 128.f) + 1e-6f);
        e0 *= rs * (1.f + nw[lane]);
        e1 *= rs * (1.f + nw[lane + 64]);
        float p = (float)posid[token];
        // inv_freq = 10000^(-lane/64); log2(10000)=13.287712379549449
        float inv = exp2f(-13.287712379549449f * ((float)lane * (1.f / 64.f)));
        float f = p * inv;
        float c = cosf(f), sn = sinf(f);
        float o0 = e0 * c - e1 * sn;
        float o1 = e1 * c + e0 * sn;
        e0 = o0; e1 = o1;
    }
    size_t dst; __bf16* out;
    if (j < 16)      { dst = ((size_t)(b * NHQ  + j)        * SEQ + s) * HDIM; out = qg; }
    else if (j < 24) { dst = ((size_t)(b * NHKV + (j - 16)) * SEQ + s) * HDIM; out = kg; }
    else             { dst = ((size_t)(b * NHKV + (j - 24)) * SEQ + s) * HDIM; out = vg; }
    out[dst + lane] = (__bf16)e0;
    out[dst + lane + 64] = (__bf16)e1;
}

// ---------------------------------------------------------------- flash attention with softcap (no online max needed: |s|<=50)
__global__ __launch_bounds__(256) void attn_k(const __bf16* __restrict__ qg,
                                              const __bf16* __restrict__ kg,
                                              const __bf16* __restrict__ vtg,
                                              const int* __restrict__ seg,
                                              const int* __restrict__ amask,
                                              __bf16* __restrict__ outg,
                                              int sliding) {
    __shared__ __align__(16) __bf16 Ks[64][136];   // [key][hd], pad 8
    __shared__ __align__(16) __bf16 Vs[128][72];   // [hd][key], pad 8
    __shared__ __align__(16) __bf16 Ps[4][16][72]; // per-wave P tile
    __shared__ int segq[64], segk[64], kmk[64];
    const int bh = blockIdx.y;
    const int b = bh >> 4, h = bh & 15, kvh = h >> 1;
    const int qb = blockIdx.x * 64;
    const int t = threadIdx.x, w = t >> 6, lane = t & 63;
    const int lg = lane >> 4, lr = lane & 15;
    const float SCALEF = 0.08838834764831845f;   // 1/sqrt(128)

    const size_t qoff = ((size_t)(b * NHQ + h) * SEQ + qb + w * 16) * HDIM;
    bf16x8 qf[4];
    #pragma unroll
    for (int kk = 0; kk < 4; ++kk)
        qf[kk] = *(const bf16x8*)&qg[qoff + (size_t)lr * HDIM + kk * 32 + lg * 8];
    if (t < 64) segq[t] = seg[b * SEQ + qb + t];

    f32x4 oacc[8] = {};
    float den[4] = {0.f, 0.f, 0.f, 0.f};
    const int sqmin = seg[b * SEQ + qb], sqmax = seg[b * SEQ + qb + 63];

    for (int kb = 0; kb < SEQ; kb += 64) {
        if (sliding && (kb + 63 < qb - 256 || kb > qb + 63 + 255)) continue;
        int skmin = seg[b * SEQ + kb], skmax = seg[b * SEQ + kb + 63];
        if (skmax < sqmin || skmin > sqmax) continue;
        // stage K chunk [64][128]
        #pragma unroll
        for (int i = 0; i < 4; ++i) {
            int c = t + i * 256;
            int row = c >> 4, part = c & 15;
            *(int4*)&Ks[row][part * 8] =
                *(const int4*)&kg[((size_t)(b * NHKV + kvh) * SEQ + kb + row) * HDIM + part * 8];
        }
        // stage V^T chunk [128][64]
        #pragma unroll
        for (int i = 0; i < 4; ++i) {
            int c = t + i * 256;
            int row = c >> 3, part = c & 7;
            *(int4*)&Vs[row][part * 8] =
                *(const int4*)&vtg[((size_t)(b * NHKV + kvh) * HDIM + row) * SEQ + kb + part * 8];
        }
        if (t < 64) { segk[t] = seg[b * SEQ + kb + t]; kmk[t] = amask[b * SEQ + kb + t]; }
        __syncthreads();
        // scores + softcap + mask + exp -> P
        #pragma unroll
        for (int n = 0; n < 4; ++n) {
            f32x4 sc = {};
            #pragma unroll
            for (int kk = 0; kk < 4; ++kk) {
                bf16x8 bfr = *(const bf16x8*)&Ks[n * 16 + lr][kk * 32 + lg * 8];
                sc = mfma16(qf[kk], bfr, sc);
            }
            #pragma unroll
            for (int r = 0; r < 4; ++r) {
                int row = lg * 4 + r;
                int qi = qb + w * 16 + row;
                int ki = kb + n * 16 + lr;
                float s = sc[r] * SCALEF;
                s = tanhf(s * 0.02f) * 50.f;
                bool ok = (kmk[n * 16 + lr] != 0) && (segq[w * 16 + row] == segk[n * 16 + lr]);
                if (sliding) { int d = qi - ki; ok = ok && (d >= -256) && (d <= 255); }
                float p = ok ? __expf(s) : 0.f;
                den[r] += p;
                Ps[w][row][n * 16 + lr] = (__bf16)p;
            }
        }
        // PV (per-wave P tile; same-wave LDS ordering)
        #pragma unroll
        for (int kk2 = 0; kk2 < 2; ++kk2) {
            bf16x8 pf = *(const bf16x8*)&Ps[w][lr][kk2 * 32 + lg * 8];
            #pragma unroll
            for (int n2 = 0; n2 < 8; ++n2) {
                bf16x8 vf = *(const bf16x8*)&Vs[n2 * 16 + lr][kk2 * 32 + lg * 8];
                oacc[n2] = mfma16(pf, vf, oacc[n2]);
            }
        }
        __syncthreads();
    }
    // reduce denominators over the 16 columns (lanes sharing lg)
    #pragma unroll
    for (int r = 0; r < 4; ++r) {
        float v = den[r];
        v += __shfl_xor(v, 1); v += __shfl_xor(v, 2);
        v += __shfl_xor(v, 4); v += __shfl_xor(v, 8);
        den[r] = v;
    }
    #pragma unroll
    for (int n2 = 0; n2 < 8; ++n2)
        #pragma unroll
        for (int r = 0; r < 4; ++r) {
            int row = qb + w * 16 + lg * 4 + r;
            float val = oacc[n2][r] / den[r];
            outg[((size_t)(b * SEQ) + row) * DMODEL + h * HDIM + n2 * 16 + lr] = (__bf16)val;
        }
}

// ---------------------------------------------------------------- GELU(gate)*up
__global__ __launch_bounds__(256) void gelu_mul(const __bf16* __restrict__ gu,
                                                __bf16* __restrict__ act) {
    const int idx = blockIdx.x * 256 + threadIdx.x;
    const int r = idx >> 10;
    const int c = (idx & 1023) * 8;
    bf16x8 g8 = *(const bf16x8*)&gu[(size_t)r * 16384 + c];
    bf16x8 u8 = *(const bf16x8*)&gu[(size_t)r * 16384 + 8192 + c];
    bf16x8 res;
    #pragma unroll
    for (int i = 0; i < 8; ++i) {
        float g = (float)g8[i], u = (float)u8[i];
        float a = 0.7978845608028654f * (g + 0.044715f * g * g * g);
        float ge = 0.5f * g * (1.f + tanhf(a));
        res[i] = (__bf16)(ge * u);
    }
    *(bf16x8*)&act[(size_t)r * 8192 + c] = res;
}

// ---------------------------------------------------------------- launch
extern "C" void kernel_launch(void* const* d_in, const int* in_sizes, int n_in,
                              void* d_out, int out_size, void* d_ws, size_t ws_size,
                              hipStream_t stream) {
    const float* embedw = (const float*)d_in[0];
    const float* wq   = (const float*)d_in[1];
    const float* wk   = (const float*)d_in[2];
    const float* wv   = (const float*)d_in[3];
    const float* wo   = (const float*)d_in[4];
    const float* qnw  = (const float*)d_in[5];
    const float* knw  = (const float*)d_in[6];
    const float* lnin = (const float*)d_in[7];
    const float* lnpa = (const float*)d_in[8];
    const float* lnpf = (const float*)d_in[9];
    const float* lnpff= (const float*)d_in[10];
    const float* wguW = (const float*)d_in[11];
    const float* wdnW = (const float*)d_in[12];
    const float* fnw  = (const float*)d_in[13];
    const int* ids    = (const int*)d_in[14];
    const int* amask  = (const int*)d_in[15];
    const int* posid  = (const int*)d_in[16];
    float* outp = (float*)d_out;

    char* ws = (char*)d_ws;
    size_t off = 0;
    auto A = [&](size_t b) -> char* {
        char* p = ws + off;
        off = (off + b + 255) & ~(size_t)255;
        return p;
    };
    __bf16* qkvwt = (__bf16*)A(2 * (size_t)4096 * 2048 * 2);
    __bf16* wot   = (__bf16*)A(2 * (size_t)2048 * 2048 * 2);
    __bf16* wgut  = (__bf16*)A(2 * (size_t)16384 * 2048 * 2);
    __bf16* wdnt  = (__bf16*)A(2 * (size_t)2048 * 8192 * 2);
    float*  x     = (float*)A((size_t)NTOK * DMODEL * 4);
    __bf16* hbuf  = (__bf16*)A((size_t)NTOK * DMODEL * 2);
    char*   big   = A((size_t)NTOK * 4096 * 4);          // qkv f32 / gu bf16 alias
    float*  qkvf  = (float*)big;
    __bf16* gubuf = (__bf16*)big;
    __bf16* qbh   = (__bf16*)A((size_t)BATCH * NHQ  * SEQ * HDIM * 2);
    __bf16* kbh   = (__bf16*)A((size_t)BATCH * NHKV * SEQ * HDIM * 2);
    __bf16* vbh   = (__bf16*)A((size_t)BATCH * NHKV * SEQ * HDIM * 2);
    __bf16* vtbh  = (__bf16*)A((size_t)BATCH * NHKV * SEQ * HDIM * 2);
    __bf16* attnb = (__bf16*)A((size_t)NTOK * DMODEL * 2);
    float*  h2    = (float*)A((size_t)NTOK * DMODEL * 4);
    __bf16* actb  = (__bf16*)A((size_t)2048 * FFDIM * 2);
    int*    seg   = (int*)A((size_t)BATCH * SEQ * 4);
    if (off > ws_size) return;   // insufficient scratch

    const dim3 tb(32, 8);
    // one-time (per call) weight convert+transpose to bf16 [N][K]
    for (int l = 0; l < 2; ++l) {
        transpose_cvt<<<dim3(64, 64), tb, 0, stream>>>(wq + (size_t)l * 2048 * 2048,
            qkvwt + (size_t)l * 4096 * 2048, 2048, 2048);
        transpose_cvt<<<dim3(32, 64), tb, 0, stream>>>(wk + (size_t)l * 2048 * 1024,
            qkvwt + (size_t)l * 4096 * 2048 + (size_t)2048 * 2048, 2048, 1024);
        transpose_cvt<<<dim3(32, 64), tb, 0, stream>>>(wv + (size_t)l * 2048 * 1024,
            qkvwt + (size_t)l * 4096 * 2048 + (size_t)3072 * 2048, 2048, 1024);
        transpose_cvt<<<dim3(64, 64), tb, 0, stream>>>(wo + (size_t)l * 2048 * 2048,
            wot + (size_t)l * 2048 * 2048, 2048, 2048);
        transpose_cvt<<<dim3(512, 64), tb, 0, stream>>>(wguW + (size_t)l * 2048 * 16384,
            wgut + (size_t)l * 16384 * 2048, 2048, 16384);
        transpose_cvt<<<dim3(64, 256), tb, 0, stream>>>(wdnW + (size_t)l * 8192 * 2048,
            wdnt + (size_t)l * 2048 * 8192, 8192, 2048);
    }
    seg_scan<<<BATCH, 256, 0, stream>>>(posid, seg);
    embed_k<<<NTOK, 256, 0, stream>>>(embedw, ids, x);
    fused_norm_k<0><<<NTOK, 256, 0, stream>>>(x, x, nullptr, lnin, hbuf, nullptr);

    for (int l = 0; l < 2; ++l) {
        const __bf16* qkvw_l = qkvwt + (size_t)l * 4096 * 2048;
        gemm_nt<float><<<dim3(32, 32), 256, 0, stream>>>(hbuf, qkvw_l, qkvf, 4096, 4096, 2048);
        qkv_post<<<32768, 256, 0, stream>>>(qkvf, qnw + l * 128, knw + l * 128, posid,
                                            qbh, kbh, vbh);
        transpose_bf16_k<<<dim3(4, 64, BATCH * NHKV), tb, 0, stream>>>(vbh, vtbh, SEQ, HDIM);
        attn_k<<<dim3(SEQ / 64, BATCH * NHQ), 256, 0, stream>>>(qbh, kbh, vtbh, seg, amask,
                                                                attnb, (l == 0) ? 1 : 0);
        gemm_nt<float><<<dim3(16, 32), 256, 0, stream>>>(attnb, wot + (size_t)l * 2048 * 2048,
                                                         h2, 4096, 2048, 2048);
        fused_norm_k<1><<<NTOK, 256, 0, stream>>>(x, h2, lnpa + l * 2048, lnpf + l * 2048,
                                                  hbuf, nullptr);
        for (int c = 0; c < 2; ++c) {
            gemm_nt<__bf16><<<dim3(128, 16), 256, 0, stream>>>(
                hbuf + (size_t)c * 2048 * 2048, wgut + (size_t)l * 16384 * 2048,
                gubuf, 2048, 16384, 2048);
            gelu_mul<<<8192, 256, 0, stream>>>(gubuf, actb);
            gemm_nt<float><<<dim3(16, 16), 256, 0, stream>>>(
                actb, wdnt + (size_t)l * 2048 * 8192,
                h2 + (size_t)c * 2048 * 2048, 2048, 2048, 8192);
        }
        if (l == 0)
            fused_norm_k<1><<<NTOK, 256, 0, stream>>>(x, h2, lnpff, lnin + 2048, hbuf, nullptr);
        else
            fused_norm_k<2><<<NTOK, 256, 0, stream>>>(x, h2, lnpff + 2048, fnw, nullptr, outp);
    }
}

// Round 2
// 1757.174 us; speedup vs baseline: 1.3026x; 1.3026x over previous
//
#include <hip/hip_runtime.h>
#include <cstdint>
#include <cstddef>

// ---------------------------------------------------------------- types
typedef __bf16 bf16x8 __attribute__((ext_vector_type(8)));
typedef float  f32x4  __attribute__((ext_vector_type(4)));

#define BATCH 2
#define SEQ   2048
#define DMODEL 2048
#define NHQ   16
#define NHKV  8
#define HDIM  128
#define FFDIM 8192
#define NTOK  4096          // BATCH*SEQ

__device__ __forceinline__ f32x4 mfma16(bf16x8 a, bf16x8 b, f32x4 c) {
    return __builtin_amdgcn_mfma_f32_16x16x32_bf16(a, b, c, 0, 0, 0);
}

__device__ __forceinline__ void gload16(const __bf16* g, __bf16* l) {
    __builtin_amdgcn_global_load_lds(
        (const __attribute__((address_space(1))) void*)g,
        (__attribute__((address_space(3))) void*)l, 16, 0, 0);
}

__device__ inline float wave_sum64(float v) {
    v += __shfl_xor(v, 1);  v += __shfl_xor(v, 2);  v += __shfl_xor(v, 4);
    v += __shfl_xor(v, 8);  v += __shfl_xor(v, 16); v += __shfl_xor(v, 32);
    return v;
}

__device__ inline float block_sum256(float v, float* lds4) {
    v = wave_sum64(v);
    const int w = threadIdx.x >> 6;
    __syncthreads();
    if ((threadIdx.x & 63) == 0) lds4[w] = v;
    __syncthreads();
    return lds4[0] + lds4[1] + lds4[2] + lds4[3];
}

// ---------------------------------------------------------------- weight convert: f32 [K][N] -> bf16 [N][K]
__global__ void transpose_cvt(const float* __restrict__ src, __bf16* __restrict__ dst,
                              int K, int N) {
    __shared__ float tile[32][33];
    const int tx = threadIdx.x, ty = threadIdx.y;
    const int n0 = blockIdx.x * 32, k0 = blockIdx.y * 32;
    #pragma unroll
    for (int i = 0; i < 4; ++i)
        tile[ty + i * 8][tx] = src[(size_t)(k0 + ty + i * 8) * N + n0 + tx];
    __syncthreads();
    #pragma unroll
    for (int i = 0; i < 4; ++i)
        dst[(size_t)(n0 + ty + i * 8) * K + k0 + tx] = (__bf16)tile[tx][ty + i * 8];
}

// bf16 [R][C] -> [C][R], per head (grid.z)
__global__ void transpose_bf16_k(const __bf16* __restrict__ src0, __bf16* __restrict__ dst0,
                                 int R, int C) {
    __shared__ __bf16 tile[32][34];
    const int z = blockIdx.z;
    const __bf16* src = src0 + (size_t)z * R * C;
    __bf16* dst = dst0 + (size_t)z * R * C;
    const int tx = threadIdx.x, ty = threadIdx.y;
    const int c0 = blockIdx.x * 32, r0 = blockIdx.y * 32;
    #pragma unroll
    for (int i = 0; i < 4; ++i)
        tile[ty + i * 8][tx] = src[(size_t)(r0 + ty + i * 8) * C + c0 + tx];
    __syncthreads();
    #pragma unroll
    for (int i = 0; i < 4; ++i)
        dst[(size_t)(c0 + ty + i * 8) * R + r0 + tx] = tile[tx][ty + i * 8];
}

// ---------------------------------------------------------------- embedding gather
__global__ __launch_bounds__(256) void embed_k(const float* __restrict__ emb,
                                               const int* __restrict__ ids,
                                               float* __restrict__ x) {
    const int row = blockIdx.x, t = threadIdx.x;
    const int id = ids[row];
    const size_t src = (size_t)id * DMODEL, dst = (size_t)row * DMODEL;
    const float sc = 45.2548339959390f;   // sqrt(2048)
    float4 a = *(const float4*)&emb[src + t * 4];
    float4 b = *(const float4*)&emb[src + t * 4 + 1024];
    a.x *= sc; a.y *= sc; a.z *= sc; a.w *= sc;
    b.x *= sc; b.y *= sc; b.z *= sc; b.w *= sc;
    *(float4*)&x[dst + t * 4] = a;
    *(float4*)&x[dst + t * 4 + 1024] = b;
}

// ---------------------------------------------------------------- segment-id scan
__global__ __launch_bounds__(256) void seg_scan(const int* __restrict__ pos,
                                                int* __restrict__ seg) {
    __shared__ int wsum[4];
    const int b = blockIdx.x, t = threadIdx.x;
    const int lane = t & 63, wv = t >> 6;
    const int base = b * SEQ;
    int f[8]; int loc = 0;
    #pragma unroll
    for (int i = 0; i < 8; ++i) {
        int s = t * 8 + i;
        int fl = (s > 0) ? (pos[base + s] <= pos[base + s - 1]) : 0;
        f[i] = fl; loc += fl;
    }
    int sc = loc;
    for (int o = 1; o < 64; o <<= 1) { int n = __shfl_up(sc, o); if (lane >= o) sc += n; }
    if (lane == 63) wsum[wv] = sc;
    __syncthreads();
    int wb = 0;
    for (int i = 0; i < wv; ++i) wb += wsum[i];
    int run = wb + sc - loc + 1;
    #pragma unroll
    for (int i = 0; i < 8; ++i) { run += f[i]; seg[base + t * 8 + i] = run; }
}

// ---------------------------------------------------------------- fused residual add + rmsnorm
// MODE 0: out_bf = rms(x, wB)
// MODE 1: x += rms(hA(+hB), wA); out_bf = rms(x, wB)
// MODE 2: x += rms(hA(+hB), wA); out_f  = rms(x, wB)
template<int MODE, int NH>
__global__ __launch_bounds__(256) void fused_norm_k(
        float* __restrict__ x, const float* __restrict__ hA, const float* __restrict__ hB,
        const float* __restrict__ wA, const float* __restrict__ wB,
        __bf16* __restrict__ outb, float* __restrict__ outf) {
    __shared__ float lds4[4];
    const int row = blockIdx.x, t = threadIdx.x;
    const size_t base = (size_t)row * DMODEL;
    const int c0 = t * 4, c1 = t * 4 + 1024;
    float v[8];
    if constexpr (MODE == 0) {
        float4 a = *(const float4*)&x[base + c0];
        float4 b = *(const float4*)&x[base + c1];
        v[0]=a.x; v[1]=a.y; v[2]=a.z; v[3]=a.w;
        v[4]=b.x; v[5]=b.y; v[6]=b.z; v[7]=b.w;
    } else {
        float4 ha = *(const float4*)&hA[base + c0];
        float4 hb = *(const float4*)&hA[base + c1];
        float hv[8] = {ha.x, ha.y, ha.z, ha.w, hb.x, hb.y, hb.z, hb.w};
        if constexpr (NH == 2) {
            float4 ga = *(const float4*)&hB[base + c0];
            float4 gb = *(const float4*)&hB[base + c1];
            hv[0]+=ga.x; hv[1]+=ga.y; hv[2]+=ga.z; hv[3]+=ga.w;
            hv[4]+=gb.x; hv[5]+=gb.y; hv[6]+=gb.z; hv[7]+=gb.w;
        }
        float ss = 0.f;
        #pragma unroll
        for (int i = 0; i < 8; ++i) ss += hv[i] * hv[i];
        float tot = block_sum256(ss, lds4);
        float rs = rsqrtf(tot * (1.f / DMODEL) + 1e-6f);
        float4 xa = *(const float4*)&x[base + c0];
        float4 xb = *(const float4*)&x[base + c1];
        float xv[8] = {xa.x, xa.y, xa.z, xa.w, xb.x, xb.y, xb.z, xb.w};
        #pragma unroll
        for (int i = 0; i < 8; ++i) {
            int c = (i < 4) ? c0 + i : c1 + i - 4;
            v[i] = xv[i] + hv[i] * rs * (1.f + wA[c]);
        }
        float4 o0 = {v[0], v[1], v[2], v[3]}, o1 = {v[4], v[5], v[6], v[7]};
        *(float4*)&x[base + c0] = o0;
        *(float4*)&x[base + c1] = o1;
    }
    float ss2 = 0.f;
    #pragma unroll
    for (int i = 0; i < 8; ++i) ss2 += v[i] * v[i];
    float tot2 = block_sum256(ss2, lds4);
    float rs2 = rsqrtf(tot2 * (1.f / DMODEL) + 1e-6f);
    #pragma unroll
    for (int i = 0; i < 8; ++i) {
        int c = (i < 4) ? c0 + i : c1 + i - 4;
        float o = v[i] * rs2 * (1.f + wB[c]);
        if constexpr (MODE == 2) outf[base + c] = o;
        else outb[base + c] = (__bf16)o;
    }
}

// ---------------------------------------------------------------- 256^2 8-phase GEMM (T1+T2+T3+T4+T5)
// C[M][N](+z*M*N) = A[M][lda](cols z*Ksub..) * Bw[N][ldb]^T (bf16 in, f32 acc)
template<int MH, int NH>
__device__ __forceinline__ void quad(f32x4 (&acc)[8][4], const bf16x8 (&af)[4][2],
                                     const bf16x8 (&bfr)[2][2]) {
    #pragma unroll
    for (int mq = 0; mq < 4; ++mq)
        #pragma unroll
        for (int nq = 0; nq < 2; ++nq)
            #pragma unroll
            for (int ks = 0; ks < 2; ++ks)
                acc[MH*4+mq][NH*2+nq] = mfma16(af[mq][ks], bfr[nq][ks], acc[MH*4+mq][NH*2+nq]);
}

template<typename OutT>
__global__ __launch_bounds__(512, 2) void gemm8p(const __bf16* __restrict__ A,
                                                 const __bf16* __restrict__ Bw,
                                                 OutT* __restrict__ C,
                                                 int M, int N, int Ksub, int lda, int ldb) {
    __shared__ __bf16 lds[65536];   // 128 KiB: [buf][A|B][half][128][64], st-swizzled
    const int z = blockIdx.z;
    A += (size_t)z * Ksub;
    Bw += (size_t)z * Ksub;
    C += (size_t)z * M * N;

    // bijective XCD swizzle (all launches have nwg % 8 == 0)
    const int nx = gridDim.x;
    const int nwg = nx * gridDim.y;
    const int orig = blockIdx.y * nx + blockIdx.x;
    const int wg = ((nwg & 7) == 0) ? ((orig & 7) * (nwg >> 3) + (orig >> 3)) : orig;
    const int bm = (wg / nx) * 256;
    const int bn = (wg % nx) * 256;

    const int t = threadIdx.x;
    const int w = t >> 6, lane = t & 63;
    const int wm = w >> 2, wn = w & 3;
    const int lg = lane >> 4, lr = lane & 15;

    // staging: thread t covers (row = t>>3, slot = t&7) of a 128x64 half-tile chunk;
    // global source column pre-swizzled so linear LDS write == swizzled layout.
    const int rS = t >> 3, sS = t & 7;
    const int colS = ((sS ^ (rS & 7)) << 3);
    const __bf16* Ag = A + (size_t)(bm + rS) * lda + colS;
    const __bf16* Bg = Bw + (size_t)(bn + rS) * ldb + colS;
    const int nt = Ksub >> 6;

#define STAGE_A(kt, h) { \
        const __bf16* g_ = Ag + (size_t)(h) * 128 * lda + (size_t)(kt) * 64; \
        const int li_ = (((kt) & 1) << 15) + ((h) << 13) + t * 8; \
        gload16(g_, &lds[li_]); \
        gload16(g_ + (size_t)64 * lda, &lds[li_ + 4096]); }
#define STAGE_B(kt, h) { \
        const __bf16* g_ = Bg + (size_t)(h) * 128 * ldb + (size_t)(kt) * 64; \
        const int li_ = (((kt) & 1) << 15) + 16384 + ((h) << 13) + t * 8; \
        gload16(g_, &lds[li_]); \
        gload16(g_ + (size_t)64 * ldb, &lds[li_ + 4096]); }

    f32x4 acc[8][4] = {};
    bf16x8 af[4][2], bf0[2][2], bf1[2][2];

    const int swz = (lr & 7) << 3;          // read-side XOR (bf16 units)
    const int aBase = wm * 8192;            // this wave's A half
    const int bBase = 16384 + (wn >> 1) * 8192;
    const int bRow0 = (wn & 1) * 64;

    // prologue: tile0 fully + A halves of tile1; keep 4 loads in flight
    STAGE_A(0, 0); STAGE_A(0, 1); STAGE_B(0, 0); STAGE_B(0, 1);
    if (nt > 1) {
        STAGE_A(1, 0); STAGE_A(1, 1);
        asm volatile("s_waitcnt vmcnt(4)" ::: "memory");
    } else {
        asm volatile("s_waitcnt vmcnt(0)" ::: "memory");
    }
    __builtin_amdgcn_s_barrier();
    asm volatile("" ::: "memory");

    for (int kt = 0; kt < nt; ++kt) {
        const int buf = (kt & 1) << 15;
        const bool p1 = (kt + 1 < nt), p2 = (kt + 2 < nt);
        // ---------- phase 0: A(mh0) + B(nh0) reads; stage B0(t+1); MFMA quad(0,0)
        #pragma unroll
        for (int mq = 0; mq < 4; ++mq)
            #pragma unroll
            for (int ks = 0; ks < 2; ++ks)
                af[mq][ks] = *(const bf16x8*)&lds[buf + aBase + (((mq*16 + lr)*64 + ks*32 + lg*8) ^ swz)];
        #pragma unroll
        for (int nq = 0; nq < 2; ++nq)
            #pragma unroll
            for (int ks = 0; ks < 2; ++ks)
                bf0[nq][ks] = *(const bf16x8*)&lds[buf + bBase + (((bRow0 + nq*16 + lr)*64 + ks*32 + lg*8) ^ swz)];
        __builtin_amdgcn_sched_barrier(0);
        if (p1) STAGE_B(kt + 1, 0);
        __builtin_amdgcn_s_barrier();
        asm volatile("s_waitcnt lgkmcnt(0)" ::: "memory");
        __builtin_amdgcn_sched_barrier(0);
        __builtin_amdgcn_s_setprio(1);
        quad<0,0>(acc, af, bf0);
        __builtin_amdgcn_s_setprio(0);
        __builtin_amdgcn_s_barrier();
        asm volatile("" ::: "memory");
        // ---------- phase 1: B(nh1) reads; stage B1(t+1); MFMA quad(0,1)
        #pragma unroll
        for (int nq = 0; nq < 2; ++nq)
            #pragma unroll
            for (int ks = 0; ks < 2; ++ks)
                bf1[nq][ks] = *(const bf16x8*)&lds[buf + bBase + (((bRow0 + 32 + nq*16 + lr)*64 + ks*32 + lg*8) ^ swz)];
        __builtin_amdgcn_sched_barrier(0);
        if (p1) STAGE_B(kt + 1, 1);
        __builtin_amdgcn_s_barrier();
        asm volatile("s_waitcnt lgkmcnt(0)" ::: "memory");
        __builtin_amdgcn_sched_barrier(0);
        __builtin_amdgcn_s_setprio(1);
        quad<0,1>(acc, af, bf1);
        __builtin_amdgcn_s_setprio(0);
        __builtin_amdgcn_s_barrier();
        asm volatile("" ::: "memory");
        // ---------- phase 2: A(mh1) reads; MFMA quad(1,1)
        #pragma unroll
        for (int mq = 0; mq < 4; ++mq)
            #pragma unroll
            for (int ks = 0; ks < 2; ++ks)
                af[mq][ks] = *(const bf16x8*)&lds[buf + aBase + (((64 + mq*16 + lr)*64 + ks*32 + lg*8) ^ swz)];
        __builtin_amdgcn_sched_barrier(0);
        __builtin_amdgcn_s_barrier();
        asm volatile("s_waitcnt lgkmcnt(0)" ::: "memory");
        __builtin_amdgcn_sched_barrier(0);
        __builtin_amdgcn_s_setprio(1);
        quad<1,1>(acc, af, bf1);
        __builtin_amdgcn_s_setprio(0);
        __builtin_amdgcn_s_barrier();
        asm volatile("" ::: "memory");
        // ---------- phase 3: stage A0,A1(t+2); counted vmcnt; MFMA quad(1,0)
        if (p2) {
            STAGE_A(kt + 2, 0); STAGE_A(kt + 2, 1);
            asm volatile("s_waitcnt vmcnt(4)" ::: "memory");
        } else if (p1) {
            asm volatile("s_waitcnt vmcnt(0)" ::: "memory");
        }
        __builtin_amdgcn_s_barrier();
        __builtin_amdgcn_sched_barrier(0);
        __builtin_amdgcn_s_setprio(1);
        quad<1,0>(acc, af, bf0);
        __builtin_amdgcn_s_setprio(0);
        __builtin_amdgcn_s_barrier();
        asm volatile("" ::: "memory");
    }
#undef STAGE_A
#undef STAGE_B

    #pragma unroll
    for (int m = 0; m < 8; ++m)
        #pragma unroll
        for (int n = 0; n < 4; ++n)
            #pragma unroll
            for (int r = 0; r < 4; ++r) {
                const int row = bm + wm * 128 + m * 16 + lg * 4 + r;
                const int col = bn + wn * 64 + n * 16 + lr;
                C[(size_t)row * N + col] = (OutT)acc[m][n][r];
            }
}

// ---------------------------------------------------------------- split-K reduce: out = sum of 4 partials
__global__ __launch_bounds__(256) void reduce4(const float* __restrict__ p,
                                               float* __restrict__ out, int n) {
    const int i = (blockIdx.x * 256 + threadIdx.x) * 4;
    float4 a = *(const float4*)&p[i];
    float4 b = *(const float4*)&p[i + n];
    float4 c = *(const float4*)&p[i + 2 * (size_t)n];
    float4 d = *(const float4*)&p[i + 3 * (size_t)n];
    float4 r = {a.x+b.x+c.x+d.x, a.y+b.y+c.y+d.y, a.z+b.z+c.z+d.z, a.w+b.w+c.w+d.w};
    *(float4*)&out[i] = r;
}

// ---------------------------------------------------------------- QKV post: per-head rmsnorm (q,k) + RoPE
__global__ __launch_bounds__(256) void qkv_post(const float* __restrict__ qkv,
                                                const float* __restrict__ qnw,
                                                const float* __restrict__ knw,
                                                const int* __restrict__ posid,
                                                __bf16* __restrict__ qg,
                                                __bf16* __restrict__ kg,
                                                __bf16* __restrict__ vg) {
    const int slot = blockIdx.x * 4 + (threadIdx.x >> 6);
    const int lane = threadIdx.x & 63;
    const int token = slot >> 5, j = slot & 31;
    const int b = token >> 11, s = token & (SEQ - 1);
    int base;
    const float* nw = nullptr;
    if (j < 16)      { base = j * 128;                nw = qnw; }
    else if (j < 24) { base = 2048 + (j - 16) * 128;  nw = knw; }
    else             { base = 3072 + (j - 24) * 128; }
    float e0 = qkv[(size_t)token * 4096 + base + lane];
    float e1 = qkv[(size_t)token * 4096 + base + lane + 64];
    if (j < 24) {
        float ss = wave_sum64(e0 * e0 + e1 * e1);
        float rs = rsqrtf(ss * (1.f / 128.f) + 1e-6f);
        e0 *= rs * (1.f + nw[lane]);
        e1 *= rs * (1.f + nw[lane + 64]);
        float p = (float)posid[token];
        float inv = exp2f(-13.287712379549449f * ((float)lane * (1.f / 64.f)));
        float f = p * inv;
        float c = cosf(f), sn = sinf(f);
        float o0 = e0 * c - e1 * sn;
        float o1 = e1 * c + e0 * sn;
        e0 = o0; e1 = o1;
    }
    size_t dst; __bf16* out;
    if (j < 16)      { dst = ((size_t)(b * NHQ  + j)        * SEQ + s) * HDIM; out = qg; }
    else if (j < 24) { dst = ((size_t)(b * NHKV + (j - 16)) * SEQ + s) * HDIM; out = kg; }
    else             { dst = ((size_t)(b * NHKV + (j - 24)) * SEQ + s) * HDIM; out = vg; }
    out[dst + lane] = (__bf16)e0;
    out[dst + lane + 64] = (__bf16)e1;
}

// ---------------------------------------------------------------- flash attention with softcap
__global__ __launch_bounds__(256) void attn_k(const __bf16* __restrict__ qg,
                                              const __bf16* __restrict__ kg,
                                              const __bf16* __restrict__ vtg,
                                              const int* __restrict__ seg,
                                              const int* __restrict__ amask,
                                              __bf16* __restrict__ outg,
                                              int sliding) {
    __shared__ __align__(16) __bf16 Ks[64][136];
    __shared__ __align__(16) __bf16 Vs[128][72];
    __shared__ __align__(16) __bf16 Ps[4][16][72];
    __shared__ int segq[64], segk[64], kmk[64];
    const int bh = blockIdx.y;
    const int b = bh >> 4, h = bh & 15, kvh = h >> 1;
    const int qb = blockIdx.x * 64;
    const int t = threadIdx.x, w = t >> 6, lane = t & 63;
    const int lg = lane >> 4, lr = lane & 15;
    const float SCALEF = 0.08838834764831845f;

    const size_t qoff = ((size_t)(b * NHQ + h) * SEQ + qb + w * 16) * HDIM;
    bf16x8 qf[4];
    #pragma unroll
    for (int kk = 0; kk < 4; ++kk)
        qf[kk] = *(const bf16x8*)&qg[qoff + (size_t)lr * HDIM + kk * 32 + lg * 8];
    if (t < 64) segq[t] = seg[b * SEQ + qb + t];

    f32x4 oacc[8] = {};
    float den[4] = {0.f, 0.f, 0.f, 0.f};
    const int sqmin = seg[b * SEQ + qb], sqmax = seg[b * SEQ + qb + 63];

    for (int kb = 0; kb < SEQ; kb += 64) {
        if (sliding && (kb + 63 < qb - 256 || kb > qb + 63 + 255)) continue;
        int skmin = seg[b * SEQ + kb], skmax = seg[b * SEQ + kb + 63];
        if (skmax < sqmin || skmin > sqmax) continue;
        #pragma unroll
        for (int i = 0; i < 4; ++i) {
            int c = t + i * 256;
            int row = c >> 4, part = c & 15;
            *(int4*)&Ks[row][part * 8] =
                *(const int4*)&kg[((size_t)(b * NHKV + kvh) * SEQ + kb + row) * HDIM + part * 8];
        }
        #pragma unroll
        for (int i = 0; i < 4; ++i) {
            int c = t + i * 256;
            int row = c >> 3, part = c & 7;
            *(int4*)&Vs[row][part * 8] =
                *(const int4*)&vtg[((size_t)(b * NHKV + kvh) * HDIM + row) * SEQ + kb + part * 8];
        }
        if (t < 64) { segk[t] = seg[b * SEQ + kb + t]; kmk[t] = amask[b * SEQ + kb + t]; }
        __syncthreads();
        #pragma unroll
        for (int n = 0; n < 4; ++n) {
            f32x4 sc = {};
            #pragma unroll
            for (int kk = 0; kk < 4; ++kk) {
                bf16x8 bfr = *(const bf16x8*)&Ks[n * 16 + lr][kk * 32 + lg * 8];
                sc = mfma16(qf[kk], bfr, sc);
            }
            #pragma unroll
            for (int r = 0; r < 4; ++r) {
                int row = lg * 4 + r;
                int qi = qb + w * 16 + row;
                int ki = kb + n * 16 + lr;
                float s = sc[r] * SCALEF;
                s = tanhf(s * 0.02f) * 50.f;
                bool ok = (kmk[n * 16 + lr] != 0) && (segq[w * 16 + row] == segk[n * 16 + lr]);
                if (sliding) { int d = qi - ki; ok = ok && (d >= -256) && (d <= 255); }
                float p = ok ? __expf(s) : 0.f;
                den[r] += p;
                Ps[w][row][n * 16 + lr] = (__bf16)p;
            }
        }
        #pragma unroll
        for (int kk2 = 0; kk2 < 2; ++kk2) {
            bf16x8 pf = *(const bf16x8*)&Ps[w][lr][kk2 * 32 + lg * 8];
            #pragma unroll
            for (int n2 = 0; n2 < 8; ++n2) {
                bf16x8 vf = *(const bf16x8*)&Vs[n2 * 16 + lr][kk2 * 32 + lg * 8];
                oacc[n2] = mfma16(pf, vf, oacc[n2]);
            }
        }
        __syncthreads();
    }
    #pragma unroll
    for (int r = 0; r < 4; ++r) {
        float v = den[r];
        v += __shfl_xor(v, 1); v += __shfl_xor(v, 2);
        v += __shfl_xor(v, 4); v += __shfl_xor(v, 8);
        den[r] = v;
    }
    #pragma unroll
    for (int n2 = 0; n2 < 8; ++n2)
        #pragma unroll
        for (int r = 0; r < 4; ++r) {
            int row = qb + w * 16 + lg * 4 + r;
            float val = oacc[n2][r] / den[r];
            outg[((size_t)(b * SEQ) + row) * DMODEL + h * HDIM + n2 * 16 + lr] = (__bf16)val;
        }
}

// ---------------------------------------------------------------- GELU(gate)*up
__global__ __launch_bounds__(256) void gelu_mul(const __bf16* __restrict__ gu,
                                                __bf16* __restrict__ act) {
    const int idx = blockIdx.x * 256 + threadIdx.x;
    const int r = idx >> 10;
    const int c = (idx & 1023) * 8;
    bf16x8 g8 = *(const bf16x8*)&gu[(size_t)r * 16384 + c];
    bf16x8 u8 = *(const bf16x8*)&gu[(size_t)r * 16384 + 8192 + c];
    bf16x8 res;
    #pragma unroll
    for (int i = 0; i < 8; ++i) {
        float g = (float)g8[i], u = (float)u8[i];
        float a = 0.7978845608028654f * (g + 0.044715f * g * g * g);
        float ge = 0.5f * g * (1.f + tanhf(a));
        res[i] = (__bf16)(ge * u);
    }
    *(bf16x8*)&act[(size_t)r * 8192 + c] = res;
}

// ---------------------------------------------------------------- launch
extern "C" void kernel_launch(void* const* d_in, const int* in_sizes, int n_in,
                              void* d_out, int out_size, void* d_ws, size_t ws_size,
                              hipStream_t stream) {
    const float* embedw = (const float*)d_in[0];
    const float* wq   = (const float*)d_in[1];
    const float* wk   = (const float*)d_in[2];
    const float* wv   = (const float*)d_in[3];
    const float* wo   = (const float*)d_in[4];
    const float* qnw  = (const float*)d_in[5];
    const float* knw  = (const float*)d_in[6];
    const float* lnin = (const float*)d_in[7];
    const float* lnpa = (const float*)d_in[8];
    const float* lnpf = (const float*)d_in[9];
    const float* lnpff= (const float*)d_in[10];
    const float* wguW = (const float*)d_in[11];
    const float* wdnW = (const float*)d_in[12];
    const float* fnw  = (const float*)d_in[13];
    const int* ids    = (const int*)d_in[14];
    const int* amask  = (const int*)d_in[15];
    const int* posid  = (const int*)d_in[16];
    float* outp = (float*)d_out;

    char* ws = (char*)d_ws;
    size_t off = 0;
    auto A = [&](size_t b) -> char* {
        char* p = ws + off;
        off = (off + b + 255) & ~(size_t)255;
        return p;
    };
    // per-layer weight buffers (converted just-in-time inside the layer loop)
    __bf16* qkvwt = (__bf16*)A((size_t)4096 * 2048 * 2);
    __bf16* wot   = (__bf16*)A((size_t)2048 * 2048 * 2);
    __bf16* wgut  = (__bf16*)A((size_t)16384 * 2048 * 2);
    __bf16* wdnt  = (__bf16*)A((size_t)2048 * 8192 * 2);
    float*  x     = (float*)A((size_t)NTOK * DMODEL * 4);
    __bf16* hbuf  = (__bf16*)A((size_t)NTOK * DMODEL * 2);
    char*   big   = A((size_t)NTOK * 4096 * 4);          // qkv f32 / gu bf16 alias
    float*  qkvf  = (float*)big;
    __bf16* gubuf = (__bf16*)big;
    __bf16* qbh   = (__bf16*)A((size_t)BATCH * NHQ  * SEQ * HDIM * 2);
    __bf16* kbh   = (__bf16*)A((size_t)BATCH * NHKV * SEQ * HDIM * 2);
    __bf16* vbh   = (__bf16*)A((size_t)BATCH * NHKV * SEQ * HDIM * 2);
    __bf16* vtbh  = (__bf16*)A((size_t)BATCH * NHKV * SEQ * HDIM * 2);
    __bf16* attnb = (__bf16*)A((size_t)NTOK * DMODEL * 2);
    float*  h2    = (float*)A((size_t)NTOK * DMODEL * 4);
    __bf16* actb  = (__bf16*)A((size_t)2048 * FFDIM * 2);
    float*  pbuf  = (float*)A((size_t)4 * 2048 * 2048 * 4);   // split-K partials
    int*    seg   = (int*)A((size_t)BATCH * SEQ * 4);
    if (off > ws_size) return;

    const dim3 tb(32, 8);
    seg_scan<<<BATCH, 256, 0, stream>>>(posid, seg);
    embed_k<<<NTOK, 256, 0, stream>>>(embedw, ids, x);
    fused_norm_k<0,1><<<NTOK, 256, 0, stream>>>(x, nullptr, nullptr, nullptr, lnin, hbuf, nullptr);

    for (int l = 0; l < 2; ++l) {
        // just-in-time weight conversion for this layer
        transpose_cvt<<<dim3(64, 64), tb, 0, stream>>>(wq + (size_t)l * 2048 * 2048,
            qkvwt, 2048, 2048);
        transpose_cvt<<<dim3(32, 64), tb, 0, stream>>>(wk + (size_t)l * 2048 * 1024,
            qkvwt + (size_t)2048 * 2048, 2048, 1024);
        transpose_cvt<<<dim3(32, 64), tb, 0, stream>>>(wv + (size_t)l * 2048 * 1024,
            qkvwt + (size_t)3072 * 2048, 2048, 1024);
        transpose_cvt<<<dim3(64, 64), tb, 0, stream>>>(wo + (size_t)l * 2048 * 2048,
            wot, 2048, 2048);
        transpose_cvt<<<dim3(512, 64), tb, 0, stream>>>(wguW + (size_t)l * 2048 * 16384,
            wgut, 2048, 16384);
        transpose_cvt<<<dim3(64, 256), tb, 0, stream>>>(wdnW + (size_t)l * 8192 * 2048,
            wdnt, 8192, 2048);

        // QKV projection (M=4096, N=4096, K=2048) -> f32
        gemm8p<float><<<dim3(16, 16, 1), 512, 0, stream>>>(hbuf, qkvwt, qkvf,
                                                           4096, 4096, 2048, 2048, 2048);
        qkv_post<<<32768, 256, 0, stream>>>(qkvf, qnw + l * 128, knw + l * 128, posid,
                                            qbh, kbh, vbh);
        transpose_bf16_k<<<dim3(4, 64, BATCH * NHKV), tb, 0, stream>>>(vbh, vtbh, SEQ, HDIM);
        attn_k<<<dim3(SEQ / 64, BATCH * NHQ), 256, 0, stream>>>(qbh, kbh, vtbh, seg, amask,
                                                                attnb, (l == 0) ? 1 : 0);
        // O projection: split-K=2 (M=4096, N=2048, Ksub=1024) -> partials, reduce fused in norm
        gemm8p<float><<<dim3(8, 16, 2), 512, 0, stream>>>(attnb, wot, pbuf,
                                                          4096, 2048, 1024, 2048, 2048);
        fused_norm_k<1,2><<<NTOK, 256, 0, stream>>>(x, pbuf, pbuf + (size_t)4096 * 2048,
                                                    lnpa + l * 2048, lnpf + l * 2048,
                                                    hbuf, nullptr);
        for (int c = 0; c < 2; ++c) {
            gemm8p<__bf16><<<dim3(64, 8, 1), 512, 0, stream>>>(
                hbuf + (size_t)c * 2048 * 2048, wgut, gubuf, 2048, 16384, 2048, 2048, 2048);
            gelu_mul<<<8192, 256, 0, stream>>>(gubuf, actb);
            // down: split-K=4 (M=2048, N=2048, Ksub=2048, ld=8192) -> 4 partials + reduce
            gemm8p<float><<<dim3(8, 8, 4), 512, 0, stream>>>(actb, wdnt, pbuf,
                                                             2048, 2048, 2048, 8192, 8192);
            reduce4<<<4096, 256, 0, stream>>>(pbuf, h2 + (size_t)c * 2048 * 2048, 2048 * 2048);
        }
        if (l == 0)
            fused_norm_k<1,1><<<NTOK, 256, 0, stream>>>(x, h2, nullptr, lnpff, lnin + 2048,
                                                        hbuf, nullptr);
        else
            fused_norm_k<2,1><<<NTOK, 256, 0, stream>>>(x, h2, nullptr, lnpff + 2048, fnw,
                                                        nullptr, outp);
    }
}